// Round 6
// baseline (305.050 us; speedup 1.0000x reference)
//
#include <hip/hip_runtime.h>
#include <hip/hip_cooperative_groups.h>

namespace cg = cooperative_groups;

#define MARGIN 1.0f
#define NT 256
#define ROWS_PER_BLOCK 8

// ---- cooperative fused kernel (compile-time C) -------------------------------
// Block b owns contiguous rows [8b, 8b+8). Flat uniform float4 stream, row
// lookup via constant-divisor magic-mul + LDS broadcast of the 8 per-row
// bias terms. Partial -> ws[blockIdx.x]; grid.sync(); block 0 reduces and
// writes the final mean. One launch, no atomics, no second kernel.
template <int CC>
__global__ __launch_bounds__(NT, 8) void mcl_coop(const float* __restrict__ score,
                                                  const int* __restrict__ target,
                                                  double* __restrict__ ws,
                                                  float* __restrict__ out,
                                                  int N) {
    constexpr int NV  = CC / 4;               // float4 per row (1250)
    constexpr int TOT = ROWS_PER_BLOCK * NV;  // float4 per block (10000)
    constexpr int KFULL = (TOT - (NT - 1) + NT - 1) / NT;  // uniform iters = 39
    constexpr int TAIL  = TOT - KFULL * NT;                // leftover slots = 16

    __shared__ float lb[ROWS_PER_BLOCK];
    {
        const int r0 = blockIdx.x * ROWS_PER_BLOCK;
        if (threadIdx.x < ROWS_PER_BLOCK) {
            const int r = r0 + threadIdx.x;
            lb[threadIdx.x] = MARGIN - score[(size_t)r * CC + target[r]];
        }
    }
    __syncthreads();

    const float4* __restrict__ rp =
        reinterpret_cast<const float4*>(score) + (size_t)blockIdx.x * TOT;

    float acc0 = 0.0f, acc1 = 0.0f;
    int f = threadIdx.x;
    #pragma unroll 3
    for (int k = 0; k < KFULL; ++k, f += NT) {   // no predication: 39*256 <= TOT
        const float b = lb[f / NV];              // constant divisor -> magic mul
        const float4 v = rp[f];
        acc0 += fmaxf(0.0f, v.x + b) + fmaxf(0.0f, v.y + b);
        acc1 += fmaxf(0.0f, v.z + b) + fmaxf(0.0f, v.w + b);
    }
    if (TAIL > 0 && threadIdx.x < TAIL) {        // 16 threads, one extra slot
        const float b = lb[f / NV];
        const float4 v = rp[f];
        acc0 += fmaxf(0.0f, v.x + b) + fmaxf(0.0f, v.y + b);
        acc1 += fmaxf(0.0f, v.z + b) + fmaxf(0.0f, v.w + b);
    }
    float acc = acc0 + acc1;

    #pragma unroll
    for (int off = 32; off > 0; off >>= 1)
        acc += __shfl_down(acc, off, 64);

    __shared__ float warp_s[NT / 64];
    if ((threadIdx.x & 63) == 0) warp_s[threadIdx.x >> 6] = acc;
    __syncthreads();
    if (threadIdx.x == 0)
        ws[blockIdx.x] = (double)(warp_s[0] + warp_s[1] + warp_s[2] + warp_s[3]);

    cg::this_grid().sync();   // device-scope release/acquire, cross-XCD safe

    if (blockIdx.x == 0) {
        const int nb = gridDim.x;
        double s = 0.0;
        for (int i = threadIdx.x; i < nb; i += NT) s += ws[i];
        #pragma unroll
        for (int off = 32; off > 0; off >>= 1)
            s += __shfl_down(s, off, 64);
        __shared__ double dsum[NT / 64];
        if ((threadIdx.x & 63) == 0) dsum[threadIdx.x >> 6] = s;
        __syncthreads();
        if (threadIdx.x == 0) {
            double tot = dsum[0] + dsum[1] + dsum[2] + dsum[3];
            tot -= (double)N * (double)MARGIN;   // remove c==target terms
            out[0] = (float)(tot / ((double)N * (double)(CC - 1)));
        }
    }
}

// ---- generic fallback (round-2 structure, 2 kernels) ------------------------
__global__ __launch_bounds__(NT) void mcl_hinge_gen(const float* __restrict__ score,
                                                    const int* __restrict__ target,
                                                    double* __restrict__ partial,
                                                    int N, int C) {
    float acc = 0.0f;
    const int nvec = C >> 2;
    for (int row = blockIdx.x; row < N; row += gridDim.x) {
        const size_t base = (size_t)row * (size_t)C;
        const float b = MARGIN - score[base + target[row]];
        const float4* __restrict__ rp = reinterpret_cast<const float4*>(score + base);
        for (int i = threadIdx.x; i < nvec; i += NT) {
            float4 v = rp[i];
            acc += fmaxf(0.0f, v.x + b) + fmaxf(0.0f, v.y + b)
                 + fmaxf(0.0f, v.z + b) + fmaxf(0.0f, v.w + b);
        }
        for (int i = (nvec << 2) + (int)threadIdx.x; i < C; i += NT)
            acc += fmaxf(0.0f, score[base + i] + b);
    }
    #pragma unroll
    for (int off = 32; off > 0; off >>= 1)
        acc += __shfl_down(acc, off, 64);
    __shared__ float warp_s[NT / 64];
    if ((threadIdx.x & 63) == 0) warp_s[threadIdx.x >> 6] = acc;
    __syncthreads();
    if (threadIdx.x == 0)
        partial[blockIdx.x] = (double)(warp_s[0] + warp_s[1] + warp_s[2] + warp_s[3]);
}

__global__ __launch_bounds__(256) void mcl_final(const double* __restrict__ partial,
                                                 float* __restrict__ out,
                                                 int NB, int N, int C) {
    double s = 0.0;
    for (int i = threadIdx.x; i < NB; i += 256) s += partial[i];
    #pragma unroll
    for (int off = 32; off > 0; off >>= 1)
        s += __shfl_down(s, off, 64);
    __shared__ double warp_s[4];
    if ((threadIdx.x & 63) == 0) warp_s[threadIdx.x >> 6] = s;
    __syncthreads();
    if (threadIdx.x == 0) {
        double tot = warp_s[0] + warp_s[1] + warp_s[2] + warp_s[3];
        tot -= (double)N * (double)MARGIN;
        out[0] = (float)(tot / ((double)N * (double)(C - 1)));
    }
}

extern "C" void kernel_launch(void* const* d_in, const int* in_sizes, int n_in,
                              void* d_out, int out_size, void* d_ws, size_t ws_size,
                              hipStream_t stream) {
    const float* score  = (const float*)d_in[0];
    const int*   target = (const int*)d_in[1];
    float* out = (float*)d_out;
    double* ws = (double*)d_ws;

    const int N = in_sizes[1];
    const int C = in_sizes[0] / N;

    if (C == 5000 && (N % ROWS_PER_BLOCK) == 0 && N / ROWS_PER_BLOCK == 2048) {
        // 2048 blocks = exactly one co-resident generation (8/CU x 256 CU),
        // guaranteed by __launch_bounds__(256, 8) -> VGPR <= 64.
        void* args[] = {(void*)&score, (void*)&target, (void*)&ws, (void*)&out, (void*)&N};
        hipLaunchCooperativeKernel((void*)mcl_coop<5000>, dim3(2048), dim3(NT),
                                   args, 0, stream);
    } else {
        const int nb = 2048;
        mcl_hinge_gen<<<nb, NT, 0, stream>>>(score, target, ws, N, C);
        mcl_final<<<1, 256, 0, stream>>>(ws, out, nb, N, C);
    }
}

// Round 7
// 58.799 us; speedup vs baseline: 5.1880x; 5.1880x over previous
//
#include <hip/hip_runtime.h>

#define MARGIN 1.0f
#define NT 256
#define ROWS_PER_BLOCK 8

// ---- specialized flat kernel (compile-time C) --------------------------------
// Block b owns contiguous rows [8b, 8b+8) = one flat 10000-float4 range.
// Threads 0-7 gather the 8 correct-class scores into LDS once; then a fully
// uniform float4 stream with row lookup via constant-divisor magic-mul + LDS
// broadcast. Best measured: 58.5 us (R4). Epilogue fusion via same-line
// atomics (R5, +12us) and grid.sync (R6, +247us) both regressed -- keep the
// plain two-kernel structure.
template <int CC>
__global__ __launch_bounds__(NT) void mcl_hinge_flat(const float* __restrict__ score,
                                                     const int* __restrict__ target,
                                                     double* __restrict__ partial) {
    constexpr int NV  = CC / 4;               // float4 per row (1250)
    constexpr int TOT = ROWS_PER_BLOCK * NV;  // float4 per block (10000)
    constexpr int KFULL = (TOT - (NT - 1) + NT - 1) / NT;  // uniform iters = 39
    constexpr int TAIL  = TOT - KFULL * NT;                // leftover slots = 16

    __shared__ float lb[ROWS_PER_BLOCK];
    const int r0 = blockIdx.x * ROWS_PER_BLOCK;
    if (threadIdx.x < ROWS_PER_BLOCK) {
        const int r = r0 + threadIdx.x;
        lb[threadIdx.x] = MARGIN - score[(size_t)r * CC + target[r]];
    }
    __syncthreads();

    const float4* __restrict__ rp =
        reinterpret_cast<const float4*>(score) + (size_t)blockIdx.x * TOT;

    float acc0 = 0.0f, acc1 = 0.0f;
    int f = threadIdx.x;
    #pragma unroll 3
    for (int k = 0; k < KFULL; ++k, f += NT) {   // no predication: 39*256 <= TOT
        const float b = lb[f / NV];              // constant divisor -> magic mul
        const float4 v = rp[f];
        acc0 += fmaxf(0.0f, v.x + b) + fmaxf(0.0f, v.y + b);
        acc1 += fmaxf(0.0f, v.z + b) + fmaxf(0.0f, v.w + b);
    }
    if (TAIL > 0 && threadIdx.x < TAIL) {        // 16 threads, one extra slot
        const float b = lb[f / NV];
        const float4 v = rp[f];
        acc0 += fmaxf(0.0f, v.x + b) + fmaxf(0.0f, v.y + b);
        acc1 += fmaxf(0.0f, v.z + b) + fmaxf(0.0f, v.w + b);
    }
    float acc = acc0 + acc1;

    #pragma unroll
    for (int off = 32; off > 0; off >>= 1)
        acc += __shfl_down(acc, off, 64);

    __shared__ float warp_s[NT / 64];
    if ((threadIdx.x & 63) == 0) warp_s[threadIdx.x >> 6] = acc;
    __syncthreads();
    if (threadIdx.x == 0)
        partial[blockIdx.x] = (double)(warp_s[0] + warp_s[1] + warp_s[2] + warp_s[3]);
}

// ---- generic fallback (round-2 structure) -----------------------------------
__global__ __launch_bounds__(NT) void mcl_hinge_gen(const float* __restrict__ score,
                                                    const int* __restrict__ target,
                                                    double* __restrict__ partial,
                                                    int N, int C) {
    float acc = 0.0f;
    const int nvec = C >> 2;
    for (int row = blockIdx.x; row < N; row += gridDim.x) {
        const size_t base = (size_t)row * (size_t)C;
        const float b = MARGIN - score[base + target[row]];
        const float4* __restrict__ rp = reinterpret_cast<const float4*>(score + base);
        for (int i = threadIdx.x; i < nvec; i += NT) {
            float4 v = rp[i];
            acc += fmaxf(0.0f, v.x + b) + fmaxf(0.0f, v.y + b)
                 + fmaxf(0.0f, v.z + b) + fmaxf(0.0f, v.w + b);
        }
        for (int i = (nvec << 2) + (int)threadIdx.x; i < C; i += NT)
            acc += fmaxf(0.0f, score[base + i] + b);
    }
    #pragma unroll
    for (int off = 32; off > 0; off >>= 1)
        acc += __shfl_down(acc, off, 64);
    __shared__ float warp_s[NT / 64];
    if ((threadIdx.x & 63) == 0) warp_s[threadIdx.x >> 6] = acc;
    __syncthreads();
    if (threadIdx.x == 0)
        partial[blockIdx.x] = (double)(warp_s[0] + warp_s[1] + warp_s[2] + warp_s[3]);
}

// ---- final reduce ------------------------------------------------------------
__global__ __launch_bounds__(256) void mcl_final(const double* __restrict__ partial,
                                                 float* __restrict__ out,
                                                 int NB, int N, int C) {
    double s = 0.0;
    for (int i = threadIdx.x; i < NB; i += 256) s += partial[i];
    #pragma unroll
    for (int off = 32; off > 0; off >>= 1)
        s += __shfl_down(s, off, 64);
    __shared__ double warp_s[4];
    if ((threadIdx.x & 63) == 0) warp_s[threadIdx.x >> 6] = s;
    __syncthreads();
    if (threadIdx.x == 0) {
        double tot = warp_s[0] + warp_s[1] + warp_s[2] + warp_s[3];
        tot -= (double)N * (double)MARGIN;   // remove the c==target terms
        out[0] = (float)(tot / ((double)N * (double)(C - 1)));
    }
}

extern "C" void kernel_launch(void* const* d_in, const int* in_sizes, int n_in,
                              void* d_out, int out_size, void* d_ws, size_t ws_size,
                              hipStream_t stream) {
    const float* score  = (const float*)d_in[0];
    const int*   target = (const int*)d_in[1];
    float* out = (float*)d_out;
    double* ws = (double*)d_ws;

    const int N = in_sizes[1];
    const int C = in_sizes[0] / N;

    if (C == 5000 && (N % ROWS_PER_BLOCK) == 0) {
        const int nb = N / ROWS_PER_BLOCK;   // 2048
        mcl_hinge_flat<5000><<<nb, NT, 0, stream>>>(score, target, ws);
        mcl_final<<<1, 256, 0, stream>>>(ws, out, nb, N, C);
    } else {
        const int nb = 2048;
        mcl_hinge_gen<<<nb, NT, 0, stream>>>(score, target, ws, N, C);
        mcl_final<<<1, 256, 0, stream>>>(ws, out, nb, N, C);
    }
}